// Round 3
// baseline (1100.280 us; speedup 1.0000x reference)
//
#include <hip/hip_runtime.h>

#define HDIM 128
#define RDIM 64
#define NLAYERS 3

// ---------------------------------------------------------------------------
// Phase 0: init degree counts (self-loop => 1) and out (= lin_b broadcast)
// ---------------------------------------------------------------------------
__global__ void k_prep(int* __restrict__ cnt, float* __restrict__ out,
                       const float* __restrict__ lin_b, int n) {
  int stride = gridDim.x * blockDim.x;
  int i0 = blockIdx.x * blockDim.x + threadIdx.x;
  for (int i = i0; i < n; i += stride) cnt[i] = 1;
  int total = n * RDIM;
  for (int i = i0; i < total; i += stride) out[i] = lin_b[i & (RDIM - 1)];
}

__global__ void k_count(const int* __restrict__ dst, int* __restrict__ cnt, int e) {
  int i = blockIdx.x * blockDim.x + threadIdx.x;
  if (i < e) atomicAdd(&cnt[dst[i]], 1);
}

__global__ void k_dis(const int* __restrict__ cnt, float* __restrict__ dis, int n) {
  int i = blockIdx.x * blockDim.x + threadIdx.x;
  if (i < n) dis[i] = rsqrtf((float)cnt[i]);   // cnt >= 1 always (self-loop)
}

// Single-block exclusive scan over n counts -> rowptr (and cursor copy).
__global__ __launch_bounds__(1024) void k_scan(const int* __restrict__ cnt,
                                               int* __restrict__ rowptr,
                                               int* __restrict__ cursor, int n) {
  __shared__ int sums[1024];
  int tid = threadIdx.x;
  int chunk = (n + 1023) >> 10;
  int lo = tid * chunk;
  int hi = min(lo + chunk, n);
  int s = 0;
  for (int i = lo; i < hi; ++i) s += cnt[i];
  sums[tid] = s;
  __syncthreads();
  for (int off = 1; off < 1024; off <<= 1) {   // Hillis-Steele inclusive scan
    int v = sums[tid];
    int add = (tid >= off) ? sums[tid - off] : 0;
    __syncthreads();
    sums[tid] = v + add;
    __syncthreads();
  }
  int run = (tid == 0) ? 0 : sums[tid - 1];
  for (int i = lo; i < hi; ++i) { rowptr[i] = run; cursor[i] = run; run += cnt[i]; }
  if (tid == 1023) rowptr[n] = sums[1023];
}

// Fill CSR buckets: entries packed {src, bits(norm)} so agg does one 8B load.
__global__ void k_fill(const int* __restrict__ src, const int* __restrict__ dst,
                       const float* __restrict__ dis, int* __restrict__ cursor,
                       int2* __restrict__ csr, int n, int e) {
  int i = blockIdx.x * blockDim.x + threadIdx.x;
  if (i < e) {
    int s = src[i], d = dst[i];
    float w = dis[s] * dis[d];
    int pos = atomicAdd(&cursor[d], 1);
    csr[pos] = make_int2(s, __float_as_int(w));
  } else if (i < e + n) {
    int v = i - e;                               // self-loop
    float dv = dis[v];
    int pos = atomicAdd(&cursor[v], 1);
    csr[pos] = make_int2(v, __float_as_int(dv * dv));
  }
}

// ---------------------------------------------------------------------------
// Tiled fp32 GEMM: C[n x COLS] (+)= A[n x 128] @ B[128 x COLS]
// Block tile 128 rows x COLS cols, KC=32 k-chunks, 8 rows x (COLS/16) cols
// per thread. sA stored transposed [k][row^((k&7)<<2)] (conflict-free b128
// reads); sB column groups permuted c^(((c>>5)&3)<<2) to balance banks.
// ---------------------------------------------------------------------------
template <int COLS, bool ACCUM>
__global__ __launch_bounds__(256) void k_gemm(const float* __restrict__ A,
                                              const float* __restrict__ B,
                                              float* __restrict__ C, int n) {
  constexpr int KC = 32;
  constexpr int LDA = 132;
  constexpr int CPT = COLS / 16;
  __shared__ float sA[KC * LDA];
  __shared__ float sB[KC * COLS];
  const int tid = threadIdx.x;
  const int cg = tid & 15;        // 16 col groups
  const int rgb = tid >> 4;       // 16 row groups of 8 rows
  const int row0 = blockIdx.x * 128;

  float acc[8][CPT];
#pragma unroll
  for (int i = 0; i < 8; ++i)
#pragma unroll
    for (int j = 0; j < CPT; ++j) acc[i][j] = 0.f;

  const int skq = tid & 7;        // staging: k-quad
  const int sr = tid >> 3;        // staging: row base (0..31)

  for (int kc = 0; kc < HDIM; kc += KC) {
    __syncthreads();
    // stage A chunk (coalesced global float4, swizzled transposed LDS store)
#pragma unroll
    for (int j = 0; j < 4; ++j) {
      int row = sr + 32 * j;
      int grow = row0 + row;
      float4 v = make_float4(0.f, 0.f, 0.f, 0.f);
      if (grow < n) v = *(const float4*)(A + (size_t)grow * HDIM + kc + skq * 4);
      int kl = skq * 4;
      sA[(kl + 0) * LDA + (row ^ (((kl + 0) & 7) << 2))] = v.x;
      sA[(kl + 1) * LDA + (row ^ (((kl + 1) & 7) << 2))] = v.y;
      sA[(kl + 2) * LDA + (row ^ (((kl + 2) & 7) << 2))] = v.z;
      sA[(kl + 3) * LDA + (row ^ (((kl + 3) & 7) << 2))] = v.w;
    }
    // stage B chunk
    constexpr int NV = KC * COLS / 4;
#pragma unroll
    for (int v4 = tid; v4 < NV; v4 += 256) {
      int k = v4 / (COLS / 4);
      int c4 = (v4 - k * (COLS / 4)) * 4;
      float4 w = *(const float4*)(B + (size_t)(kc + k) * COLS + c4);
      int cp = c4 ^ (((c4 >> 5) & 3) << 2);
      *(float4*)(&sB[k * COLS + cp]) = w;
    }
    __syncthreads();
#pragma unroll 4
    for (int k = 0; k < KC; ++k) {
      int msk = (k & 7) << 2;
      float a[8];
      {
        float4 a0 = *(const float4*)(&sA[k * LDA + ((rgb * 8) ^ msk)]);
        float4 a1 = *(const float4*)(&sA[k * LDA + ((rgb * 8 + 4) ^ msk)]);
        a[0] = a0.x; a[1] = a0.y; a[2] = a0.z; a[3] = a0.w;
        a[4] = a1.x; a[5] = a1.y; a[6] = a1.z; a[7] = a1.w;
      }
      float b[CPT];
#pragma unroll
      for (int s = 0; s < CPT / 4; ++s) {
        int c0 = cg * CPT + s * 4;
        int cp = c0 ^ (((c0 >> 5) & 3) << 2);
        float4 w = *(const float4*)(&sB[k * COLS + cp]);
        b[s * 4 + 0] = w.x; b[s * 4 + 1] = w.y;
        b[s * 4 + 2] = w.z; b[s * 4 + 3] = w.w;
      }
#pragma unroll
      for (int i = 0; i < 8; ++i)
#pragma unroll
        for (int j = 0; j < CPT; ++j) acc[i][j] = fmaf(a[i], b[j], acc[i][j]);
    }
  }
  // epilogue
#pragma unroll
  for (int i = 0; i < 8; ++i) {
    int grow = row0 + rgb * 8 + i;
    if (grow < n) {
#pragma unroll
      for (int s = 0; s < CPT / 4; ++s) {
        float4 o;
        o.x = acc[i][s * 4 + 0]; o.y = acc[i][s * 4 + 1];
        o.z = acc[i][s * 4 + 2]; o.w = acc[i][s * 4 + 3];
        float* cp = C + (size_t)grow * COLS + cg * CPT + s * 4;
        if (ACCUM) {
          float4 prev = *(const float4*)cp;
          o.x += prev.x; o.y += prev.y; o.z += prev.z; o.w += prev.w;
        }
        *(float4*)cp = o;
      }
    }
  }
}

// ---------------------------------------------------------------------------
// CSR-gather aggregation: one wave per node, lane owns 2 feature channels.
// hout[v] = relu( sum_{(u,w) in CSR[v]} t[u]*w + bias )
// ---------------------------------------------------------------------------
__global__ __launch_bounds__(256) void k_agg(const float* __restrict__ t,
                                             const int* __restrict__ rowptr,
                                             const int2* __restrict__ csr,
                                             const float* __restrict__ bias,
                                             float* __restrict__ hout, int n) {
  const int lane = threadIdx.x & 63;
  const int f = lane * 2;
  const float2 bv = *(const float2*)(bias + f);
  const int wid = blockIdx.x * 4 + (threadIdx.x >> 6);
  const int nw = gridDim.x * 4;
  for (int v = wid; v < n; v += nw) {
    const int e0 = rowptr[v];
    const int e1 = rowptr[v + 1];
    float ax = 0.f, ay = 0.f;
    int e = e0;
    for (; e + 1 < e1; e += 2) {     // 2-edge unroll: two rows in flight
      int2 c0 = csr[e];
      int2 c1 = csr[e + 1];
      float2 t0 = *(const float2*)(t + (size_t)c0.x * HDIM + f);
      float2 t1 = *(const float2*)(t + (size_t)c1.x * HDIM + f);
      float w0 = __int_as_float(c0.y);
      float w1 = __int_as_float(c1.y);
      ax = fmaf(t0.x, w0, ax); ay = fmaf(t0.y, w0, ay);
      ax = fmaf(t1.x, w1, ax); ay = fmaf(t1.y, w1, ay);
    }
    if (e < e1) {
      int2 c0 = csr[e];
      float2 t0 = *(const float2*)(t + (size_t)c0.x * HDIM + f);
      float w0 = __int_as_float(c0.y);
      ax = fmaf(t0.x, w0, ax); ay = fmaf(t0.y, w0, ay);
    }
    float2 hv;
    hv.x = fmaxf(ax + bv.x, 0.f);
    hv.y = fmaxf(ay + bv.y, 0.f);
    *(float2*)(hout + (size_t)v * HDIM + f) = hv;
  }
}

// ---------------------------------------------------------------------------
extern "C" void kernel_launch(void* const* d_in, const int* in_sizes, int n_in,
                              void* d_out, int out_size, void* d_ws, size_t ws_size,
                              hipStream_t stream) {
  (void)n_in; (void)out_size; (void)ws_size;
  const float* x  = (const float*)d_in[0];
  const int*   ei = (const int*)d_in[1];
  const float* Ws = (const float*)d_in[2];
  const float* bs = (const float*)d_in[3];
  const float* lw = (const float*)d_in[4];
  const float* lb = (const float*)d_in[5];
  float* out = (float*)d_out;

  const int n = in_sizes[0] / HDIM;
  const int e = in_sizes[1] / 2;
  const int* src = ei;
  const int* dst = ei + e;

  // workspace carve-out (~118 MB total)
  char* p = (char*)d_ws;
  auto take = [&](size_t bytes) {
    char* r = p;
    p += (bytes + 255) & ~(size_t)255;
    return (void*)r;
  };
  int*   cnt    = (int*)take((size_t)n * 4);
  int*   rowptr = (int*)take((size_t)(n + 1) * 4);
  int*   cursor = (int*)take((size_t)n * 4);
  float* dis    = (float*)take((size_t)n * 4);
  int2*  csr    = (int2*)take((size_t)(e + n) * 8);
  float* tbuf   = (float*)take((size_t)n * HDIM * 4);
  float* hbuf   = (float*)take((size_t)n * HDIM * 4);

  // CSR build (once; reused by all 3 layers)
  k_prep<<<1024, 256, 0, stream>>>(cnt, out, lb, n);
  k_count<<<(e + 255) / 256, 256, 0, stream>>>(dst, cnt, e);
  k_dis<<<(n + 255) / 256, 256, 0, stream>>>(cnt, dis, n);
  k_scan<<<1, 1024, 0, stream>>>(cnt, rowptr, cursor, n);
  k_fill<<<(e + n + 255) / 256, 256, 0, stream>>>(src, dst, dis, cursor, csr, n, e);

  // 3 GCN layers; output projection fused per layer (out pre-seeded with lin_b)
  const int gtiles = (n + 127) / 128;
  const float* hin = x;
  for (int l = 0; l < NLAYERS; ++l) {
    k_gemm<HDIM, false><<<gtiles, 256, 0, stream>>>(
        hin, Ws + (size_t)l * HDIM * HDIM, tbuf, n);
    k_agg<<<2048, 256, 0, stream>>>(
        tbuf, rowptr, csr, bs + (size_t)l * HDIM, hbuf, n);
    k_gemm<RDIM, true><<<gtiles, 256, 0, stream>>>(
        hbuf, lw + (size_t)l * HDIM * RDIM, out, n);
    hin = hbuf;
  }
}

// Round 4
// 879.587 us; speedup vs baseline: 1.2509x; 1.2509x over previous
//
#include <hip/hip_runtime.h>

#define HDIM 128
#define RDIM 64
#define NLAYERS 3

// ---------------------------------------------------------------------------
// Phase 0: init degree counts (self-loop => 1) and out (= lin_b broadcast)
// ---------------------------------------------------------------------------
__global__ void k_prep(int* __restrict__ cnt, float* __restrict__ out,
                       const float* __restrict__ lin_b, int n) {
  int stride = gridDim.x * blockDim.x;
  int i0 = blockIdx.x * blockDim.x + threadIdx.x;
  for (int i = i0; i < n; i += stride) cnt[i] = 1;
  int total = n * RDIM;
  for (int i = i0; i < total; i += stride) out[i] = lin_b[i & (RDIM - 1)];
}

__global__ void k_count(const int* __restrict__ dst, int* __restrict__ cnt, int e) {
  int i = blockIdx.x * blockDim.x + threadIdx.x;
  if (i < e) atomicAdd(&cnt[dst[i]], 1);
}

// ---------------------------------------------------------------------------
// Two-level parallel exclusive scan over cnt[] -> rowptr/cursor (+ dis fused).
// Level 1: per-block (1024 elems) reduce.
// ---------------------------------------------------------------------------
__global__ __launch_bounds__(1024) void k_scan1(const int* __restrict__ cnt,
                                                int* __restrict__ bsum, int n) {
  __shared__ int red[16];
  int tid = threadIdx.x;
  int gid = blockIdx.x * 1024 + tid;
  int v = (gid < n) ? cnt[gid] : 0;
#pragma unroll
  for (int off = 1; off < 64; off <<= 1) v += __shfl_xor(v, off);
  if ((tid & 63) == 0) red[tid >> 6] = v;
  __syncthreads();
  if (tid < 16) {
    int s = red[tid];
#pragma unroll
    for (int off = 1; off < 16; off <<= 1) s += __shfl_xor(s, off, 16);
    if (tid == 0) bsum[blockIdx.x] = s;
  }
}

// Level 2: one wave scans the <=1k block sums (carry loop), exclusive -> boff.
__global__ __launch_bounds__(64) void k_scan2(const int* __restrict__ bsum,
                                              int* __restrict__ boff,
                                              int* __restrict__ rowptr,
                                              int nb, int n) {
  int lane = threadIdx.x;
  int carry = 0;
  for (int base = 0; base < nb; base += 64) {
    int i = base + lane;
    int v = (i < nb) ? bsum[i] : 0;
    int incl = v;
#pragma unroll
    for (int off = 1; off < 64; off <<= 1) {
      int t = __shfl_up(incl, off);
      if (lane >= off) incl += t;
    }
    if (i < nb) boff[i] = carry + incl - v;
    carry += __shfl(incl, 63);
  }
  if (lane == 0) rowptr[n] = carry;
}

// Level 3: per-block inclusive scan + block offset -> rowptr/cursor; dis fused.
__global__ __launch_bounds__(1024) void k_scan3(const int* __restrict__ cnt,
                                                const int* __restrict__ boff,
                                                int* __restrict__ rowptr,
                                                int* __restrict__ cursor,
                                                float* __restrict__ dis, int n) {
  __shared__ int wsum[16];
  int tid = threadIdx.x;
  int gid = blockIdx.x * 1024 + tid;
  int lane = tid & 63, wave = tid >> 6;
  int v = (gid < n) ? cnt[gid] : 0;
  int incl = v;
#pragma unroll
  for (int off = 1; off < 64; off <<= 1) {
    int t = __shfl_up(incl, off);
    if (lane >= off) incl += t;
  }
  if (lane == 63) wsum[wave] = incl;
  __syncthreads();
  if (tid < 16) {
    int s = wsum[tid];
    int is = s;
#pragma unroll
    for (int off = 1; off < 16; off <<= 1) {
      int t = __shfl_up(is, off, 16);
      if (tid >= off) is += t;
    }
    wsum[tid] = is - s;   // exclusive wave offset within block
  }
  __syncthreads();
  if (gid < n) {
    int exc = boff[blockIdx.x] + wsum[wave] + incl - v;
    rowptr[gid] = exc;
    cursor[gid] = exc;
    dis[gid] = rsqrtf((float)v);   // v >= 1 (self-loop)
  }
}

// Fill CSR buckets: entries packed {src, bits(norm)} so agg does one 8B load.
__global__ void k_fill(const int* __restrict__ src, const int* __restrict__ dst,
                       const float* __restrict__ dis, int* __restrict__ cursor,
                       int2* __restrict__ csr, int n, int e) {
  int i = blockIdx.x * blockDim.x + threadIdx.x;
  if (i < e) {
    int s = src[i], d = dst[i];
    float w = dis[s] * dis[d];
    int pos = atomicAdd(&cursor[d], 1);
    csr[pos] = make_int2(s, __float_as_int(w));
  } else if (i < e + n) {
    int v = i - e;                               // self-loop
    float dv = dis[v];
    int pos = atomicAdd(&cursor[v], 1);
    csr[pos] = make_int2(v, __float_as_int(dv * dv));
  }
}

// ---------------------------------------------------------------------------
// Tiled fp32 GEMM: C[n x COLS] (+)= A[n x 128] @ B[128 x COLS]
// Block tile 128 rows x COLS cols, KC=32 k-chunks, 8 rows x (COLS/16) cols
// per thread. sA stored transposed [k][row^((k&7)<<2)] (conflict-free b128
// reads); sB column groups permuted c^(((c>>5)&3)<<2) to balance banks.
// ---------------------------------------------------------------------------
template <int COLS, bool ACCUM>
__global__ __launch_bounds__(256) void k_gemm(const float* __restrict__ A,
                                              const float* __restrict__ B,
                                              float* __restrict__ C, int n) {
  constexpr int KC = 32;
  constexpr int LDA = 132;
  constexpr int CPT = COLS / 16;
  __shared__ float sA[KC * LDA];
  __shared__ float sB[KC * COLS];
  const int tid = threadIdx.x;
  const int cg = tid & 15;        // 16 col groups
  const int rgb = tid >> 4;       // 16 row groups of 8 rows
  const int row0 = blockIdx.x * 128;

  float acc[8][CPT];
#pragma unroll
  for (int i = 0; i < 8; ++i)
#pragma unroll
    for (int j = 0; j < CPT; ++j) acc[i][j] = 0.f;

  const int skq = tid & 7;        // staging: k-quad
  const int sr = tid >> 3;        // staging: row base (0..31)

  for (int kc = 0; kc < HDIM; kc += KC) {
    __syncthreads();
    // stage A chunk (coalesced global float4, swizzled transposed LDS store)
#pragma unroll
    for (int j = 0; j < 4; ++j) {
      int row = sr + 32 * j;
      int grow = row0 + row;
      float4 v = make_float4(0.f, 0.f, 0.f, 0.f);
      if (grow < n) v = *(const float4*)(A + (size_t)grow * HDIM + kc + skq * 4);
      int kl = skq * 4;
      sA[(kl + 0) * LDA + (row ^ (((kl + 0) & 7) << 2))] = v.x;
      sA[(kl + 1) * LDA + (row ^ (((kl + 1) & 7) << 2))] = v.y;
      sA[(kl + 2) * LDA + (row ^ (((kl + 2) & 7) << 2))] = v.z;
      sA[(kl + 3) * LDA + (row ^ (((kl + 3) & 7) << 2))] = v.w;
    }
    // stage B chunk
    constexpr int NV = KC * COLS / 4;
#pragma unroll
    for (int v4 = tid; v4 < NV; v4 += 256) {
      int k = v4 / (COLS / 4);
      int c4 = (v4 - k * (COLS / 4)) * 4;
      float4 w = *(const float4*)(B + (size_t)(kc + k) * COLS + c4);
      int cp = c4 ^ (((c4 >> 5) & 3) << 2);
      *(float4*)(&sB[k * COLS + cp]) = w;
    }
    __syncthreads();
#pragma unroll 4
    for (int k = 0; k < KC; ++k) {
      int msk = (k & 7) << 2;
      float a[8];
      {
        float4 a0 = *(const float4*)(&sA[k * LDA + ((rgb * 8) ^ msk)]);
        float4 a1 = *(const float4*)(&sA[k * LDA + ((rgb * 8 + 4) ^ msk)]);
        a[0] = a0.x; a[1] = a0.y; a[2] = a0.z; a[3] = a0.w;
        a[4] = a1.x; a[5] = a1.y; a[6] = a1.z; a[7] = a1.w;
      }
      float b[CPT];
#pragma unroll
      for (int s = 0; s < CPT / 4; ++s) {
        int c0 = cg * CPT + s * 4;
        int cp = c0 ^ (((c0 >> 5) & 3) << 2);
        float4 w = *(const float4*)(&sB[k * COLS + cp]);
        b[s * 4 + 0] = w.x; b[s * 4 + 1] = w.y;
        b[s * 4 + 2] = w.z; b[s * 4 + 3] = w.w;
      }
#pragma unroll
      for (int i = 0; i < 8; ++i)
#pragma unroll
        for (int j = 0; j < CPT; ++j) acc[i][j] = fmaf(a[i], b[j], acc[i][j]);
    }
  }
  // epilogue
#pragma unroll
  for (int i = 0; i < 8; ++i) {
    int grow = row0 + rgb * 8 + i;
    if (grow < n) {
#pragma unroll
      for (int s = 0; s < CPT / 4; ++s) {
        float4 o;
        o.x = acc[i][s * 4 + 0]; o.y = acc[i][s * 4 + 1];
        o.z = acc[i][s * 4 + 2]; o.w = acc[i][s * 4 + 3];
        float* cp = C + (size_t)grow * COLS + cg * CPT + s * 4;
        if (ACCUM) {
          float4 prev = *(const float4*)cp;
          o.x += prev.x; o.y += prev.y; o.z += prev.z; o.w += prev.w;
        }
        *(float4*)cp = o;
      }
    }
  }
}

// ---------------------------------------------------------------------------
// CSR-gather aggregation: one wave per node, lane owns 2 feature channels.
// hout[v] = relu( sum_{(u,w) in CSR[v]} t[u]*w + bias )
// ---------------------------------------------------------------------------
__global__ __launch_bounds__(256) void k_agg(const float* __restrict__ t,
                                             const int* __restrict__ rowptr,
                                             const int2* __restrict__ csr,
                                             const float* __restrict__ bias,
                                             float* __restrict__ hout, int n) {
  const int lane = threadIdx.x & 63;
  const int f = lane * 2;
  const float2 bv = *(const float2*)(bias + f);
  const int wid = blockIdx.x * 4 + (threadIdx.x >> 6);
  const int nw = gridDim.x * 4;
  for (int v = wid; v < n; v += nw) {
    const int e0 = rowptr[v];
    const int e1 = rowptr[v + 1];
    float ax = 0.f, ay = 0.f;
    int e = e0;
    for (; e + 1 < e1; e += 2) {     // 2-edge unroll: two rows in flight
      int2 c0 = csr[e];
      int2 c1 = csr[e + 1];
      float2 t0 = *(const float2*)(t + (size_t)c0.x * HDIM + f);
      float2 t1 = *(const float2*)(t + (size_t)c1.x * HDIM + f);
      float w0 = __int_as_float(c0.y);
      float w1 = __int_as_float(c1.y);
      ax = fmaf(t0.x, w0, ax); ay = fmaf(t0.y, w0, ay);
      ax = fmaf(t1.x, w1, ax); ay = fmaf(t1.y, w1, ay);
    }
    if (e < e1) {
      int2 c0 = csr[e];
      float2 t0 = *(const float2*)(t + (size_t)c0.x * HDIM + f);
      float w0 = __int_as_float(c0.y);
      ax = fmaf(t0.x, w0, ax); ay = fmaf(t0.y, w0, ay);
    }
    float2 hv;
    hv.x = fmaxf(ax + bv.x, 0.f);
    hv.y = fmaxf(ay + bv.y, 0.f);
    *(float2*)(hout + (size_t)v * HDIM + f) = hv;
  }
}

// ---------------------------------------------------------------------------
extern "C" void kernel_launch(void* const* d_in, const int* in_sizes, int n_in,
                              void* d_out, int out_size, void* d_ws, size_t ws_size,
                              hipStream_t stream) {
  (void)n_in; (void)out_size; (void)ws_size;
  const float* x  = (const float*)d_in[0];
  const int*   ei = (const int*)d_in[1];
  const float* Ws = (const float*)d_in[2];
  const float* bs = (const float*)d_in[3];
  const float* lw = (const float*)d_in[4];
  const float* lb = (const float*)d_in[5];
  float* out = (float*)d_out;

  const int n = in_sizes[0] / HDIM;
  const int e = in_sizes[1] / 2;
  const int* src = ei;
  const int* dst = ei + e;
  const int nb = (n + 1023) / 1024;   // scan level-1 block count

  // workspace carve-out (~118 MB total)
  char* p = (char*)d_ws;
  auto take = [&](size_t bytes) {
    char* r = p;
    p += (bytes + 255) & ~(size_t)255;
    return (void*)r;
  };
  int*   cnt    = (int*)take((size_t)n * 4);
  int*   rowptr = (int*)take((size_t)(n + 1) * 4);
  int*   cursor = (int*)take((size_t)n * 4);
  float* dis    = (float*)take((size_t)n * 4);
  int*   bsum   = (int*)take((size_t)nb * 4);
  int*   boff   = (int*)take((size_t)nb * 4);
  int2*  csr    = (int2*)take((size_t)(e + n) * 8);
  float* tbuf   = (float*)take((size_t)n * HDIM * 4);
  float* hbuf   = (float*)take((size_t)n * HDIM * 4);

  // CSR build (once; reused by all 3 layers)
  k_prep<<<1024, 256, 0, stream>>>(cnt, out, lb, n);
  k_count<<<(e + 255) / 256, 256, 0, stream>>>(dst, cnt, e);
  k_scan1<<<nb, 1024, 0, stream>>>(cnt, bsum, n);
  k_scan2<<<1, 64, 0, stream>>>(bsum, boff, rowptr, nb, n);
  k_scan3<<<nb, 1024, 0, stream>>>(cnt, boff, rowptr, cursor, dis, n);
  k_fill<<<(e + n + 255) / 256, 256, 0, stream>>>(src, dst, dis, cursor, csr, n, e);

  // 3 GCN layers; output projection fused per layer (out pre-seeded with lin_b)
  const int gtiles = (n + 127) / 128;
  const float* hin = x;
  for (int l = 0; l < NLAYERS; ++l) {
    k_gemm<HDIM, false><<<gtiles, 256, 0, stream>>>(
        hin, Ws + (size_t)l * HDIM * HDIM, tbuf, n);
    k_agg<<<2048, 256, 0, stream>>>(
        tbuf, rowptr, csr, bs + (size_t)l * HDIM, hbuf, n);
    k_gemm<RDIM, true><<<gtiles, 256, 0, stream>>>(
        hbuf, lw + (size_t)l * HDIM * RDIM, out, n);
    hin = hbuf;
  }
}

// Round 5
// 691.901 us; speedup vs baseline: 1.5902x; 1.2713x over previous
//
#include <hip/hip_runtime.h>

#define HDIM 128
#define RDIM 64
#define NLAYERS 3

typedef unsigned int uint32;
typedef unsigned short ushort16;

// round-to-nearest-even fp32 -> bf16 (as raw ushort)
__device__ __forceinline__ ushort16 f2bf_rne(float x) {
  uint32 u = __float_as_uint(x);
  u += 0x7FFFu + ((u >> 16) & 1u);
  return (ushort16)(u >> 16);
}
__device__ __forceinline__ float bf_lo(uint32 p) { return __uint_as_float(p << 16); }
__device__ __forceinline__ float bf_hi(uint32 p) { return __uint_as_float(p & 0xFFFF0000u); }

// ---------------------------------------------------------------------------
// Phase 0: init degree counts (self-loop => 1) and out (= lin_b broadcast)
// ---------------------------------------------------------------------------
__global__ void k_prep(int* __restrict__ cnt, float* __restrict__ out,
                       const float* __restrict__ lin_b, int n) {
  int stride = gridDim.x * blockDim.x;
  int i0 = blockIdx.x * blockDim.x + threadIdx.x;
  for (int i = i0; i < n; i += stride) cnt[i] = 1;
  int total = n * RDIM;
  for (int i = i0; i < total; i += stride) out[i] = lin_b[i & (RDIM - 1)];
}

__global__ void k_count(const int* __restrict__ dst, int* __restrict__ cnt, int e) {
  int i = blockIdx.x * blockDim.x + threadIdx.x;
  if (i < e) atomicAdd(&cnt[dst[i]], 1);
}

// ---------------------------------------------------------------------------
// Two-level parallel exclusive scan over cnt[] -> rowptr/cursor (+ dis fused).
// ---------------------------------------------------------------------------
__global__ __launch_bounds__(1024) void k_scan1(const int* __restrict__ cnt,
                                                int* __restrict__ bsum, int n) {
  __shared__ int red[16];
  int tid = threadIdx.x;
  int gid = blockIdx.x * 1024 + tid;
  int v = (gid < n) ? cnt[gid] : 0;
#pragma unroll
  for (int off = 1; off < 64; off <<= 1) v += __shfl_xor(v, off);
  if ((tid & 63) == 0) red[tid >> 6] = v;
  __syncthreads();
  if (tid < 16) {
    int s = red[tid];
#pragma unroll
    for (int off = 1; off < 16; off <<= 1) s += __shfl_xor(s, off, 16);
    if (tid == 0) bsum[blockIdx.x] = s;
  }
}

__global__ __launch_bounds__(64) void k_scan2(const int* __restrict__ bsum,
                                              int* __restrict__ boff,
                                              int* __restrict__ rowptr,
                                              int nb, int n) {
  int lane = threadIdx.x;
  int carry = 0;
  for (int base = 0; base < nb; base += 64) {
    int i = base + lane;
    int v = (i < nb) ? bsum[i] : 0;
    int incl = v;
#pragma unroll
    for (int off = 1; off < 64; off <<= 1) {
      int t = __shfl_up(incl, off);
      if (lane >= off) incl += t;
    }
    if (i < nb) boff[i] = carry + incl - v;
    carry += __shfl(incl, 63);
  }
  if (lane == 0) rowptr[n] = carry;
}

__global__ __launch_bounds__(1024) void k_scan3(const int* __restrict__ cnt,
                                                const int* __restrict__ boff,
                                                int* __restrict__ rowptr,
                                                int* __restrict__ cursor,
                                                float* __restrict__ dis, int n) {
  __shared__ int wsum[16];
  int tid = threadIdx.x;
  int gid = blockIdx.x * 1024 + tid;
  int lane = tid & 63, wave = tid >> 6;
  int v = (gid < n) ? cnt[gid] : 0;
  int incl = v;
#pragma unroll
  for (int off = 1; off < 64; off <<= 1) {
    int t = __shfl_up(incl, off);
    if (lane >= off) incl += t;
  }
  if (lane == 63) wsum[wave] = incl;
  __syncthreads();
  if (tid < 16) {
    int s = wsum[tid];
    int is = s;
#pragma unroll
    for (int off = 1; off < 16; off <<= 1) {
      int t = __shfl_up(is, off, 16);
      if (tid >= off) is += t;
    }
    wsum[tid] = is - s;   // exclusive wave offset within block
  }
  __syncthreads();
  if (gid < n) {
    int exc = boff[blockIdx.x] + wsum[wave] + incl - v;
    rowptr[gid] = exc;
    cursor[gid] = exc;
    dis[gid] = rsqrtf((float)v);   // v >= 1 (self-loop)
  }
}

// Fill CSR buckets: entries packed {src, bits(norm)} so agg does one 8B load.
__global__ void k_fill(const int* __restrict__ src, const int* __restrict__ dst,
                       const float* __restrict__ dis, int* __restrict__ cursor,
                       int2* __restrict__ csr, int n, int e) {
  int i = blockIdx.x * blockDim.x + threadIdx.x;
  if (i < e) {
    int s = src[i], d = dst[i];
    float w = dis[s] * dis[d];
    int pos = atomicAdd(&cursor[d], 1);
    csr[pos] = make_int2(s, __float_as_int(w));
  } else if (i < e + n) {
    int v = i - e;                               // self-loop
    float dv = dis[v];
    int pos = atomicAdd(&cursor[v], 1);
    csr[pos] = make_int2(v, __float_as_int(dv * dv));
  }
}

// ---------------------------------------------------------------------------
// Tiled fp32 GEMM: C[n x COLS] (+)= A[n x 128] @ B[128 x COLS]
// BF16OUT: epilogue converts to bf16 (RNE) — used for tbuf (agg's gather src).
// ---------------------------------------------------------------------------
template <int COLS, bool ACCUM, bool BF16OUT>
__global__ __launch_bounds__(256) void k_gemm(const float* __restrict__ A,
                                              const float* __restrict__ B,
                                              void* __restrict__ Cv, int n) {
  constexpr int KC = 32;
  constexpr int LDA = 132;
  constexpr int CPT = COLS / 16;
  __shared__ float sA[KC * LDA];
  __shared__ float sB[KC * COLS];
  const int tid = threadIdx.x;
  const int cg = tid & 15;        // 16 col groups
  const int rgb = tid >> 4;       // 16 row groups of 8 rows
  const int row0 = blockIdx.x * 128;

  float acc[8][CPT];
#pragma unroll
  for (int i = 0; i < 8; ++i)
#pragma unroll
    for (int j = 0; j < CPT; ++j) acc[i][j] = 0.f;

  const int skq = tid & 7;        // staging: k-quad
  const int sr = tid >> 3;        // staging: row base (0..31)

  for (int kc = 0; kc < HDIM; kc += KC) {
    __syncthreads();
#pragma unroll
    for (int j = 0; j < 4; ++j) {
      int row = sr + 32 * j;
      int grow = row0 + row;
      float4 v = make_float4(0.f, 0.f, 0.f, 0.f);
      if (grow < n) v = *(const float4*)(A + (size_t)grow * HDIM + kc + skq * 4);
      int kl = skq * 4;
      sA[(kl + 0) * LDA + (row ^ (((kl + 0) & 7) << 2))] = v.x;
      sA[(kl + 1) * LDA + (row ^ (((kl + 1) & 7) << 2))] = v.y;
      sA[(kl + 2) * LDA + (row ^ (((kl + 2) & 7) << 2))] = v.z;
      sA[(kl + 3) * LDA + (row ^ (((kl + 3) & 7) << 2))] = v.w;
    }
    constexpr int NV = KC * COLS / 4;
#pragma unroll
    for (int v4 = tid; v4 < NV; v4 += 256) {
      int k = v4 / (COLS / 4);
      int c4 = (v4 - k * (COLS / 4)) * 4;
      float4 w = *(const float4*)(B + (size_t)(kc + k) * COLS + c4);
      int cp = c4 ^ (((c4 >> 5) & 3) << 2);
      *(float4*)(&sB[k * COLS + cp]) = w;
    }
    __syncthreads();
#pragma unroll 4
    for (int k = 0; k < KC; ++k) {
      int msk = (k & 7) << 2;
      float a[8];
      {
        float4 a0 = *(const float4*)(&sA[k * LDA + ((rgb * 8) ^ msk)]);
        float4 a1 = *(const float4*)(&sA[k * LDA + ((rgb * 8 + 4) ^ msk)]);
        a[0] = a0.x; a[1] = a0.y; a[2] = a0.z; a[3] = a0.w;
        a[4] = a1.x; a[5] = a1.y; a[6] = a1.z; a[7] = a1.w;
      }
      float b[CPT];
#pragma unroll
      for (int s = 0; s < CPT / 4; ++s) {
        int c0 = cg * CPT + s * 4;
        int cp = c0 ^ (((c0 >> 5) & 3) << 2);
        float4 w = *(const float4*)(&sB[k * COLS + cp]);
        b[s * 4 + 0] = w.x; b[s * 4 + 1] = w.y;
        b[s * 4 + 2] = w.z; b[s * 4 + 3] = w.w;
      }
#pragma unroll
      for (int i = 0; i < 8; ++i)
#pragma unroll
        for (int j = 0; j < CPT; ++j) acc[i][j] = fmaf(a[i], b[j], acc[i][j]);
    }
  }
  // epilogue
#pragma unroll
  for (int i = 0; i < 8; ++i) {
    int grow = row0 + rgb * 8 + i;
    if (grow < n) {
#pragma unroll
      for (int s = 0; s < CPT / 4; ++s) {
        float4 o;
        o.x = acc[i][s * 4 + 0]; o.y = acc[i][s * 4 + 1];
        o.z = acc[i][s * 4 + 2]; o.w = acc[i][s * 4 + 3];
        if (BF16OUT) {
          ushort16* Cb = (ushort16*)Cv;
          uint32 lo = (uint32)f2bf_rne(o.x) | ((uint32)f2bf_rne(o.y) << 16);
          uint32 hi = (uint32)f2bf_rne(o.z) | ((uint32)f2bf_rne(o.w) << 16);
          uint2 pk; pk.x = lo; pk.y = hi;
          *(uint2*)(Cb + (size_t)grow * COLS + cg * CPT + s * 4) = pk;
        } else {
          float* C = (float*)Cv;
          float* cp = C + (size_t)grow * COLS + cg * CPT + s * 4;
          if (ACCUM) {
            float4 prev = *(const float4*)cp;
            o.x += prev.x; o.y += prev.y; o.z += prev.z; o.w += prev.w;
          }
          *(float4*)cp = o;
        }
      }
    }
  }
}

// ---------------------------------------------------------------------------
// CSR-gather aggregation over bf16 t. One wave per node; each HALF-wave
// (32 lanes x 8B = one full 256B bf16 row) owns one edge -> 2 edges per
// wave-instruction, 4 edges in flight in the main loop. Lane covers 4
// features; halves are folded with shfl_xor(32) at the end.
// hout[v] = relu( sum_{(u,w) in CSR[v]} t[u]*w + bias )   (fp32 out)
// ---------------------------------------------------------------------------
__global__ __launch_bounds__(256) void k_agg(const ushort16* __restrict__ tb,
                                             const int* __restrict__ rowptr,
                                             const int2* __restrict__ csr,
                                             const float* __restrict__ bias,
                                             float* __restrict__ hout, int n) {
  const int lane = threadIdx.x & 63;
  const int half = lane >> 5;          // which edge of the pair
  const int fl = (lane & 31) * 4;      // feature base (4 bf16 = 8B per lane)
  const float4 bv = *(const float4*)(bias + fl);
  const int wid = blockIdx.x * 4 + (threadIdx.x >> 6);
  const int nw = gridDim.x * 4;
  for (int v = wid; v < n; v += nw) {
    const int e0 = rowptr[v];
    const int e1 = rowptr[v + 1];
    float4 acc = make_float4(0.f, 0.f, 0.f, 0.f);
    int e = e0;
    for (; e + 3 < e1; e += 4) {       // 4 edges/iter, loads issued up front
      int2 cA = csr[e + half];
      int2 cB = csr[e + 2 + half];
      uint2 ta = *(const uint2*)(tb + ((size_t)cA.x << 7) + fl);
      uint2 tc = *(const uint2*)(tb + ((size_t)cB.x << 7) + fl);
      float wA = __int_as_float(cA.y);
      float wB = __int_as_float(cB.y);
      acc.x = fmaf(bf_lo(ta.x), wA, acc.x);
      acc.y = fmaf(bf_hi(ta.x), wA, acc.y);
      acc.z = fmaf(bf_lo(ta.y), wA, acc.z);
      acc.w = fmaf(bf_hi(ta.y), wA, acc.w);
      acc.x = fmaf(bf_lo(tc.x), wB, acc.x);
      acc.y = fmaf(bf_hi(tc.x), wB, acc.y);
      acc.z = fmaf(bf_lo(tc.y), wB, acc.z);
      acc.w = fmaf(bf_hi(tc.y), wB, acc.w);
    }
    for (; e < e1; e += 2) {           // masked tail (handles 1-3 leftovers)
      int idx = e + half;
      int2 c = (idx < e1) ? csr[idx] : make_int2(0, 0);
      uint2 ta = *(const uint2*)(tb + ((size_t)c.x << 7) + fl);
      float w = __int_as_float(c.y);
      acc.x = fmaf(bf_lo(ta.x), w, acc.x);
      acc.y = fmaf(bf_hi(ta.x), w, acc.y);
      acc.z = fmaf(bf_lo(ta.y), w, acc.z);
      acc.w = fmaf(bf_hi(ta.y), w, acc.w);
    }
    // fold the two half-wave partial sums
    acc.x += __shfl_xor(acc.x, 32);
    acc.y += __shfl_xor(acc.y, 32);
    acc.z += __shfl_xor(acc.z, 32);
    acc.w += __shfl_xor(acc.w, 32);
    if (half == 0) {
      float4 hv;
      hv.x = fmaxf(acc.x + bv.x, 0.f);
      hv.y = fmaxf(acc.y + bv.y, 0.f);
      hv.z = fmaxf(acc.z + bv.z, 0.f);
      hv.w = fmaxf(acc.w + bv.w, 0.f);
      *(float4*)(hout + (size_t)v * HDIM + fl) = hv;
    }
  }
}

// ---------------------------------------------------------------------------
extern "C" void kernel_launch(void* const* d_in, const int* in_sizes, int n_in,
                              void* d_out, int out_size, void* d_ws, size_t ws_size,
                              hipStream_t stream) {
  (void)n_in; (void)out_size; (void)ws_size;
  const float* x  = (const float*)d_in[0];
  const int*   ei = (const int*)d_in[1];
  const float* Ws = (const float*)d_in[2];
  const float* bs = (const float*)d_in[3];
  const float* lw = (const float*)d_in[4];
  const float* lb = (const float*)d_in[5];
  float* out = (float*)d_out;

  const int n = in_sizes[0] / HDIM;
  const int e = in_sizes[1] / 2;
  const int* src = ei;
  const int* dst = ei + e;
  const int nb = (n + 1023) / 1024;   // scan level-1 block count

  // workspace carve-out
  char* p = (char*)d_ws;
  auto take = [&](size_t bytes) {
    char* r = p;
    p += (bytes + 255) & ~(size_t)255;
    return (void*)r;
  };
  int*      cnt    = (int*)take((size_t)n * 4);
  int*      rowptr = (int*)take((size_t)(n + 1) * 4);
  int*      cursor = (int*)take((size_t)n * 4);
  float*    dis    = (float*)take((size_t)n * 4);
  int*      bsum   = (int*)take((size_t)nb * 4);
  int*      boff   = (int*)take((size_t)nb * 4);
  int2*     csr    = (int2*)take((size_t)(e + n) * 8);
  ushort16* tbuf   = (ushort16*)take((size_t)n * HDIM * 2);   // bf16 t
  float*    hbuf   = (float*)take((size_t)n * HDIM * 4);

  // CSR build (once; reused by all 3 layers)
  k_prep<<<1024, 256, 0, stream>>>(cnt, out, lb, n);
  k_count<<<(e + 255) / 256, 256, 0, stream>>>(dst, cnt, e);
  k_scan1<<<nb, 1024, 0, stream>>>(cnt, bsum, n);
  k_scan2<<<1, 64, 0, stream>>>(bsum, boff, rowptr, nb, n);
  k_scan3<<<nb, 1024, 0, stream>>>(cnt, boff, rowptr, cursor, dis, n);
  k_fill<<<(e + n + 255) / 256, 256, 0, stream>>>(src, dst, dis, cursor, csr, n, e);

  // 3 GCN layers; output projection fused per layer (out pre-seeded with lin_b)
  const int gtiles = (n + 127) / 128;
  const float* hin = x;
  for (int l = 0; l < NLAYERS; ++l) {
    k_gemm<HDIM, false, true><<<gtiles, 256, 0, stream>>>(
        hin, Ws + (size_t)l * HDIM * HDIM, tbuf, n);
    k_agg<<<2048, 256, 0, stream>>>(
        tbuf, rowptr, csr, bs + (size_t)l * HDIM, hbuf, n);
    k_gemm<RDIM, true, false><<<gtiles, 256, 0, stream>>>(
        hbuf, lw + (size_t)l * HDIM * RDIM, out, n);
    hin = hbuf;
  }
}